// Round 8
// baseline (264.318 us; speedup 1.0000x reference)
//
#include <hip/hip_runtime.h>
#include <hip/hip_cooperative_groups.h>
#include <stdint.h>

namespace cg = cooperative_groups;

#define NPIX   131072      // 32*64*64 per batch
#define HALFN  65536
#define KSEL   50
#define CAP_E  1024        // easy candidate cap (u >= THR)
#define CAP_H  2048        // hard prefix length / cap
#define THR    0.99f
#define CSTR   32          // counter stride in ints (128 B: one cacheline per counter)
#define SENT_HARD 0xFFFFFFFFu
#define SENT_NONE 0xFFFFFFFEu
#define NBLK   256
#define NTHR   512
#define NWAVE  (NTHR / 64)

__host__ __device__ __forceinline__ uint32_t rotl32(uint32_t v, int d) {
  return (v << d) | (v >> (32 - d));
}

// JAX Threefry-2x32 block (20 rounds), matches jax/_src/prng.py exactly.
__host__ __device__ __forceinline__ void tf_block(uint32_t k0, uint32_t k1,
                                                  uint32_t c0, uint32_t c1,
                                                  uint32_t& o0, uint32_t& o1) {
  uint32_t ks2 = k0 ^ k1 ^ 0x1BD11BDAu;
  uint32_t x0 = c0 + k0, x1 = c1 + k1;
#define TF_R(r) { x0 += x1; x1 = rotl32(x1, (r)); x1 ^= x0; }
  TF_R(13) TF_R(15) TF_R(26) TF_R(6)   x0 += k1;  x1 += ks2 + 1u;
  TF_R(17) TF_R(29) TF_R(16) TF_R(24)  x0 += ks2; x1 += k0  + 2u;
  TF_R(13) TF_R(15) TF_R(26) TF_R(6)   x0 += k0;  x1 += k1  + 3u;
  TF_R(17) TF_R(29) TF_R(16) TF_R(24)  x0 += k1;  x1 += ks2 + 4u;
  TF_R(13) TF_R(15) TF_R(26) TF_R(6)   x0 += ks2; x1 += k0  + 5u;
#undef TF_R
  o0 = x0; o1 = x1;
}

__device__ __forceinline__ bool cond_eval(uint32_t s, int cid) {
  // 0: non-easy, 1: hard, 2: non-hard
  return cid == 0 ? (s >= SENT_NONE) : (cid == 1 ? (s == SENT_HARD) : (s != SENT_HARD));
}

// want-th (0-based) smallest index n with cond over one batch's scores; NTHR threads.
// foundcnt = number actually found (= want+1 on success).
__device__ int nth_min_pred(const uint32_t* __restrict__ sc, int want, int cid,
                            int tid, int lane, int wv, uint32_t* s_w32, int* foundcnt) {
  int prev = -1;
  int k = 0;
  for (; k <= want; ++k) {
    uint32_t lmin = 0xFFFFFFFFu;
    for (int m = tid; m < NPIX; m += NTHR) {
      if (cond_eval(sc[m], cid) && m > prev && (uint32_t)m < lmin) lmin = (uint32_t)m;
    }
    for (int off = 32; off; off >>= 1) {
      uint32_t o = (uint32_t)__shfl_down(lmin, off);
      if (o < lmin) lmin = o;
    }
    if (lane == 0) s_w32[wv] = lmin;
    __syncthreads();
    if (tid == 0) {
      uint32_t g = 0xFFFFFFFFu;
      for (int w = 0; w < NWAVE; ++w) if (s_w32[w] < g) g = s_w32[w];
      s_w32[0] = g;
    }
    __syncthreads();
    uint32_t g = s_w32[0];
    __syncthreads();   // guard before next-iteration writes to s_w32
    if (g == 0xFFFFFFFFu) break;
    prev = (int)g;
  }
  *foundcnt = k;
  return prev;
}

// Single cooperative kernel: zero -> scores/compact -> selgather -> loss.
__global__ __launch_bounds__(NTHR) void k_fused(
    const int* __restrict__ labels, const int* __restrict__ predict,
    const float* __restrict__ feats,
    uint32_t* __restrict__ scores, uint64_t* __restrict__ ecand,
    uint32_t* __restrict__ hcand, int* __restrict__ cnts,
    float* __restrict__ A, float* __restrict__ out,
    uint32_t k00, uint32_t k01, uint32_t k10, uint32_t k11) {
  cg::grid_group grid = cg::this_grid();
  int tid = threadIdx.x, lane = tid & 63, wv = tid >> 6;
  int blk = blockIdx.x;

  __shared__ int we[NWAVE], wh[NWAVE], wec[NWAVE], whc[NWAVE];
  __shared__ int base_ec, base_hc;
  __shared__ uint64_t se[CAP_E];     // 8 KB
  __shared__ uint32_t shd[CAP_H];    // 8 KB
  __shared__ uint32_t s_w32[NWAVE];
  __shared__ uint64_t s_w64[NWAVE];
  __shared__ int s_n;
  __shared__ float red[NTHR];
  __shared__ float arow[128];
  __shared__ float wsum[2];
  __shared__ float s_inv;

  // ---------------- Phase 0: zero counters + out ----------------
  if (blk == 0) {
    if (tid < 8 * CSTR) cnts[tid] = 0;
    if (tid == 0) out[0] = 0.f;
  }
  grid.sync();

  // ---------------- Phase 1: scores + block-aggregated compaction ----------------
  for (int c = 0; c < 2; ++c) {
    int gid = blk * (2 * NTHR) + c * NTHR + tid;   // 256*1024 = 2*NPIX exact
    int b = gid >> 17;
    int n = gid & (NPIX - 1);
    int yh = labels[gid], yp = predict[gid];
    bool is_easy = (yh == 1 && yp == 1);
    bool is_hard = (yh == 0 && yp == 0);
    uint32_t sval = SENT_NONE;
    float u = -1.f;
    if (is_easy) {
      uint32_t ka = b ? k10 : k00, kb = b ? k11 : k01;
      uint32_t o0, o1, bits;
      if (n < HALFN) { tf_block(ka, kb, (uint32_t)n, (uint32_t)(n + HALFN), o0, o1); bits = o0; }
      else           { tf_block(ka, kb, (uint32_t)(n - HALFN), (uint32_t)n, o0, o1); bits = o1; }
      u = __uint_as_float((bits >> 9) | 0x3F800000u) - 1.0f;   // jax uniform [0,1)
      sval = __float_as_uint(u);
    } else if (is_hard) {
      sval = SENT_HARD;
    }
    scores[gid] = sval;

    bool cand_e = is_easy && (u >= THR);
    bool cand_h = is_hard && (n < CAP_H);
    uint64_t bal_e  = __ballot(is_easy), bal_h  = __ballot(is_hard);
    uint64_t bal_ec = __ballot(cand_e),  bal_hc = __ballot(cand_h);

    if (lane == 0) {
      we[wv]  = __popcll(bal_e);  wh[wv]  = __popcll(bal_h);
      wec[wv] = __popcll(bal_ec); whc[wv] = __popcll(bal_hc);
    }
    __syncthreads();
    if (tid == 0) {
      int te = 0, th = 0, tec = 0, thc = 0;
      for (int w = 0; w < NWAVE; ++w) { te += we[w]; th += wh[w]; tec += wec[w]; thc += whc[w]; }
      if (te) atomicAdd(&cnts[(b * 4 + 0) * CSTR], te);
      if (th) atomicAdd(&cnts[(b * 4 + 2) * CSTR], th);
      base_ec = tec ? atomicAdd(&cnts[(b * 4 + 1) * CSTR], tec) : 0;
      base_hc = thc ? atomicAdd(&cnts[(b * 4 + 3) * CSTR], thc) : 0;
    }
    __syncthreads();
    if (cand_e) {
      int pre = 0;
      for (int w = 0; w < wv; ++w) pre += wec[w];
      int p = base_ec + pre + __popcll(bal_ec & ((1ull << lane) - 1));
      if (p < CAP_E)
        ecand[b * CAP_E + p] = ((uint64_t)sval << 32) | (uint32_t)(~(uint32_t)n);
    }
    if (cand_h) {
      int pre = 0;
      for (int w = 0; w < wv; ++w) pre += whc[w];
      int p = base_hc + pre + __popcll(bal_hc & ((1ull << lane) - 1));
      hcand[b * CAP_H + p] = (uint32_t)n;   // <= CAP_H guaranteed (subset of n<CAP_H)
    }
    __syncthreads();   // guard before next-iteration writes to we/wh/wec/whc
  }
  grid.sync();

  // ---------------- Phase 2: select + gather + normalize (blocks 0..199) ----------------
  if (blk < 200) {
    int r = blk;                 // row 0..199; A[2i+v] = X_[v][i]
    int v = r & 1, i = r >> 1;
    int b = v;
    const uint32_t* sc = scores + (size_t)b * NPIX;

    int et = cnts[(b * 4 + 0) * CSTR], ec = cnts[(b * 4 + 1) * CSTR];
    int ht = cnts[(b * 4 + 2) * CSTR], hc = cnts[(b * 4 + 3) * CSTR];

    if (i < KSEL) {
      // easy row: rank i of top_k
      int eneed = et < KSEL ? et : KSEL;
      bool fast = (ec <= CAP_E) && (ec >= eneed);
      if (fast) {
        int take = ec < KSEL ? ec : KSEL;
        if (i < take) {
          for (int t = tid; t < ec; t += NTHR) se[t] = ecand[b * CAP_E + t];
          __syncthreads();
          for (int t = tid; t < ec; t += NTHR) {
            uint64_t mine = se[t];
            int rank = 0;
            for (int j = 0; j < ec; ++j) rank += (se[j] > mine);
            if (rank == i) s_n = (int)(~(uint32_t)mine);
          }
          __syncthreads();
        } else {
          int fc;
          int nsel = nth_min_pred(sc, i - take, 0, tid, lane, wv, s_w32, &fc);
          if (tid == 0) s_n = nsel;
          __syncthreads();
        }
      } else {
        // slow exact (never taken on bench data)
        uint64_t prev = 0xFFFFFFFFFFFFFFFFull;
        int found = 0, nsel = -1;
        for (int k = 0; k <= i; ++k) {
          uint64_t lmax = 0;
          for (int m = tid; m < NPIX; m += NTHR) {
            uint32_t s = sc[m];
            if (s < SENT_NONE) {
              uint64_t key = ((uint64_t)s << 32) | (uint32_t)(~(uint32_t)m);
              if (key < prev && key > lmax) lmax = key;
            }
          }
          for (int off = 32; off; off >>= 1) {
            uint64_t o = __shfl_down(lmax, off);
            if (o > lmax) lmax = o;
          }
          if (lane == 0) s_w64[wv] = lmax;
          __syncthreads();
          if (tid == 0) {
            uint64_t g = 0;
            for (int w = 0; w < NWAVE; ++w) if (s_w64[w] > g) g = s_w64[w];
            s_w64[0] = g;
          }
          __syncthreads();
          uint64_t g = s_w64[0];
          __syncthreads();
          if (g == 0) break;
          prev = g; found = k + 1;
          if (k == i) nsel = (int)(~(uint32_t)g);
        }
        if (nsel < 0) {
          int fc;
          nsel = nth_min_pred(sc, i - found, 0, tid, lane, wv, s_w32, &fc);
        }
        if (tid == 0) s_n = nsel;
        __syncthreads();
      }
    } else {
      // hard row: j-th smallest hard index
      int j = i - KSEL;
      int hneed = ht < KSEL ? ht : KSEL;
      bool fast = (hc >= hneed);   // hc <= CAP_H always
      if (fast) {
        int take = hc < KSEL ? hc : KSEL;
        if (j < take) {
          for (int t = tid; t < hc; t += NTHR) shd[t] = hcand[b * CAP_H + t];
          __syncthreads();
          for (int t = tid; t < hc; t += NTHR) {
            uint32_t mine = shd[t];
            int rank = 0;
            for (int m = 0; m < hc; ++m) rank += (shd[m] < mine);
            if (rank == j) s_n = (int)mine;
          }
          __syncthreads();
        } else {
          int fc;
          int nsel = nth_min_pred(sc, j - take, 2, tid, lane, wv, s_w32, &fc);
          if (tid == 0) s_n = nsel;
          __syncthreads();
        }
      } else {
        // slow exact (never taken on bench data)
        int fc = 0;
        int nsel = nth_min_pred(sc, j, 1, tid, lane, wv, s_w32, &fc);
        if (fc < j + 1) {
          int fc2;
          nsel = nth_min_pred(sc, j - fc, 2, tid, lane, wv, s_w32, &fc2);
        }
        if (tid == 0) s_n = nsel;
        __syncthreads();
      }
    }

    int n = s_n;
    // gather + L2-normalize (feats layout [B, D=128, NPIX]); threads 0..127 only
    if (tid < 128) {
      float val = feats[((size_t)(v * 128 + tid)) * NPIX + (size_t)n];
      float sq = val * val;
      for (int off = 32; off; off >>= 1) sq += __shfl_down(sq, off);
      if (lane == 0) wsum[wv] = sq;     // wv = 0 or 1 for tid<128
      red[tid] = val;                   // stash val across the syncthreads
    }
    __syncthreads();
    if (tid == 0) s_inv = 1.0f / fmaxf(sqrtf(wsum[0] + wsum[1]), 1e-12f);
    __syncthreads();
    if (tid < 128) A[r * 128 + tid] = red[tid] * s_inv;
  }
  grid.sync();

  // ---------------- Phase 3: contrastive loss (blocks 0..199) ----------------
  if (blk < 200) {
    int r = blk;
    if (tid < 128) arow[tid] = A[r * 128 + tid];
    __syncthreads();
    bool valid = tid < 200;
    float logit = -1e30f;
    if (valid) {
      const float* Ac = A + tid * 128;
      float dot = 0.f;
#pragma unroll 8
      for (int d = 0; d < 128; ++d) dot += arow[d] * Ac[d];
      logit = dot * 10.0f;      // / BASE_TEMP (0.1)
    }
    red[tid] = logit;
    __syncthreads();
    for (int s = NTHR / 2; s; s >>= 1) { if (tid < s) { float o = red[tid + s]; if (o > red[tid]) red[tid] = o; } __syncthreads(); }
    float M = red[0];
    __syncthreads();
    float e = valid ? expf(logit - M) : 0.f;
    bool sameblk = valid && ((r / 100) == (tid / 100));
    red[tid] = (valid && !sameblk) ? e : 0.f;   // neg_mask = 1 - mask0
    __syncthreads();
    for (int s = NTHR / 2; s; s >>= 1) { if (tid < s) red[tid] += red[tid + s]; __syncthreads(); }
    float neg = red[0];
    __syncthreads();
    bool msk = sameblk && !(r < 100 && tid == r);   // mask0 * logits_mask
    red[tid] = msk ? ((logit - M) - logf(e + neg)) : 0.f;
    __syncthreads();
    for (int s = NTHR / 2; s; s >>= 1) { if (tid < s) red[tid] += red[tid + s]; __syncthreads(); }
    if (tid == 0) {
      float denom = (r < 100) ? 99.f : 100.f;
      // -(mean_lpp / TEMP).mean() accumulated across 200 rows
      atomicAdd(out, -(red[0] / denom) / (20.0f * 200.0f));
    }
  }
}

extern "C" void kernel_launch(void* const* d_in, const int* in_sizes, int n_in,
                              void* d_out, int out_size, void* d_ws, size_t ws_size,
                              hipStream_t stream) {
  const float* feats  = (const float*)d_in[0];
  const int* labels   = (const int*)d_in[1];
  const int* predict  = (const int*)d_in[2];
  float* out = (float*)d_out;

  char* ws = (char*)d_ws;
  uint32_t* scores = (uint32_t*)ws;                            // 1 MiB
  uint64_t* ecand  = (uint64_t*)(ws + (size_t)2 * NPIX * 4);   // 2*1024 u64 = 16 KB
  uint32_t* hcand  = (uint32_t*)((char*)ecand + 2 * CAP_E * 8);// 2*2048 u32 = 16 KB
  int* cnts  = (int*)((char*)hcand + 2 * CAP_H * 4);           // 8*CSTR int
  float* A   = (float*)(cnts + 8 * CSTR);                      // 200*128 f32

  // Batch keys: key(42) = (0,42); split -> blocks (0,2) and (1,3) (host-side, deterministic).
  uint32_t a0, a1, b0, b1;
  tf_block(0u, 42u, 0u, 2u, a0, a1);
  tf_block(0u, 42u, 1u, 3u, b0, b1);
  // keys[0] = (a0, b0), keys[1] = (a1, b1)

  void* args[] = {(void*)&labels, (void*)&predict, (void*)&feats,
                  (void*)&scores, (void*)&ecand, (void*)&hcand, (void*)&cnts,
                  (void*)&A, (void*)&out,
                  (void*)&a0, (void*)&b0, (void*)&a1, (void*)&b1};
  hipLaunchCooperativeKernel((void*)k_fused, dim3(NBLK), dim3(NTHR), args, 0, stream);
}